// Round 12
// baseline (303.166 us; speedup 1.0000x reference)
//
#include <hip/hip_runtime.h>
#include <hip/hip_bf16.h>

typedef unsigned short u16;
typedef unsigned int   u32;
typedef __attribute__((ext_vector_type(8))) short short8;
typedef __attribute__((ext_vector_type(4))) float floatx4;
typedef __attribute__((ext_vector_type(4))) unsigned short u16x4;

__device__ __forceinline__ u16 f2bf(float f){
  u32 x = __float_as_uint(f);
  u32 r = (x + 0x7fffu + ((x >> 16) & 1u)) >> 16;   // RNE
  return (u16)r;
}
__device__ __forceinline__ float bf2f(u16 u){
  return __uint_as_float(((u32)u) << 16);
}
// fast tanh: (e-1)/(e+1), e = 2^(2x*log2e). |err| < ~1e-5, invisible in bf16.
__device__ __forceinline__ float tanh_fast(float x){
  float xs = fminf(fmaxf(x, -16.f), 16.f);
  float e  = __builtin_amdgcn_exp2f(xs * 2.8853900817779268f);
  return (e - 1.f) * __builtin_amdgcn_rcpf(e + 1.f);
}
// async global->LDS, 16B per lane; LDS dest is wave-uniform base + lane*16
__device__ __forceinline__ void gload16(const void* g, void* l){
  __builtin_amdgcn_global_load_lds(
      (const __attribute__((address_space(1))) unsigned int*)g,
      (__attribute__((address_space(3))) unsigned int*)l, 16, 0, 0);
}

// ---- MFMA-frag-major layout for GEMM A-operands ----------------------------
// elem(row,k) lives at ((row>>4)*10 + (k>>5))*512 + (((k>>3)&3)*16 + (row&15))*8 + (k&7)
// => one A-frag (16 rows x 32 k) = 1KB contiguous; a wave's global_load_dwordx4
//    at base + lane*16B is perfectly coalesced.  dcol must be 4-aligned.
__device__ __forceinline__ size_t fmaddr(int row, int dcol){
  return (size_t)((row >> 4) * 10 + (dcol >> 5)) * 512
       + (size_t)((((dcol >> 3) & 3) << 4) + (row & 15)) * 8 + (dcol & 7);
}

// B=64, L=1000, D=300 padded to 320; V=50000
// ---------------- K1: FUSED gather + bf16 cast + s2/s4/s10 segment sums -----
// Writes x and s2/s4/s10 in frag-major layout.
__global__ void k_gather_seg(const int* __restrict__ idx, const float* __restrict__ emb,
                             u16* __restrict__ x, u16* __restrict__ s2,
                             u16* __restrict__ s4, u16* __restrict__ s10, int total){
  int i = blockIdx.x * blockDim.x + threadIdx.x;
  if (i >= total) return;
  int d4 = i % 80; int rest = i / 80; int w = rest % 50; int b = rest / 50;
  const int dcol = d4 * 4;
  const int r0 = b * 1000 + w * 20;
  float a2[4] = {0,0,0,0}, a4[4] = {0,0,0,0}, a10[4] = {0,0,0,0};
  #pragma unroll
  for (int j = 0; j < 20; j++){
    const int r = r0 + j;
    u16x4 o; o[0] = 0; o[1] = 0; o[2] = 0; o[3] = 0;
    if (d4 < 75){
      const float4 v = *(const float4*)(emb + (size_t)idx[r] * 300 + dcol);
      o[0] = f2bf(v.x); o[1] = f2bf(v.y); o[2] = f2bf(v.z); o[3] = f2bf(v.w);
      a2[0] += v.x; a2[1] += v.y; a2[2] += v.z; a2[3] += v.w;
      a4[0] += v.x; a4[1] += v.y; a4[2] += v.z; a4[3] += v.w;
      a10[0] += v.x; a10[1] += v.y; a10[2] += v.z; a10[3] += v.w;
    }
    *(u16x4*)(x + fmaddr(r, dcol)) = o;
    if (j & 1){
      u16x4 s;
      #pragma unroll
      for (int q = 0; q < 4; q++){ s[q] = f2bf(a2[q]); a2[q] = 0.f; }
      *(u16x4*)(s2 + fmaddr(b * 500 + w * 10 + (j >> 1), dcol)) = s;
    }
    if ((j & 3) == 3){
      u16x4 s;
      #pragma unroll
      for (int q = 0; q < 4; q++){ s[q] = f2bf(a4[q]); a4[q] = 0.f; }
      *(u16x4*)(s4 + fmaddr(b * 250 + w * 5 + (j >> 2), dcol)) = s;
    }
    if (j == 9 || j == 19){
      u16x4 s;
      #pragma unroll
      for (int q = 0; q < 4; q++){ s[q] = f2bf(a10[q]); a10[q] = 0.f; }
      *(u16x4*)(s10 + fmaddr(b * 100 + w * 2 + j / 10, dcol)) = s;
    }
  }
}

// ---------------- K2: s25 from x (both frag-major) --------------------------
__global__ void k_s25(const u16* __restrict__ x, u16* __restrict__ s25, int total){
  int i = blockIdx.x * blockDim.x + threadIdx.x;
  if (i >= total) return;
  int d4 = i % 80; int rest = i / 80; int g = rest % 40; int b = rest / 40;
  const int dcol = d4 * 4;
  float a[4] = {0,0,0,0};
  #pragma unroll
  for (int j = 0; j < 25; j++){
    u16x4 v = *(const u16x4*)(x + fmaddr(b * 1000 + g * 25 + j, dcol));
    #pragma unroll
    for (int q = 0; q < 4; q++) a[q] += bf2f(v[q]);
  }
  u16x4 o;
  #pragma unroll
  for (int q = 0; q < 4; q++) o[q] = f2bf(a[q]);
  *(u16x4*)(s25 + fmaddr(b * 40 + g, dcol)) = o;
}

// ---------------- K3: pack weights transposed+padded: wT[mat][n*320+k] ------
__global__ void k_wprep(const float* __restrict__ wce, const float* __restrict__ wz,
                        const float* __restrict__ wo, u16* __restrict__ wT, int total){
  int i = blockIdx.x * blockDim.x + threadIdx.x;
  if (i >= total) return;
  int mat = i / 102400; int rem = i - mat * 102400;
  int n = rem / 320;    int k = rem - n * 320;
  float v = 0.f;
  if (n < 300 && k < 300){
    const float* src = (mat < 5) ? (wce + mat * 90000) : (mat == 5 ? wz : wo);
    v = src[k * 300 + n];
  }
  wT[i] = f2bf(v);
}

// ---------------- K4: ALL GEMMs — W-resident LDS + coalesced A streaming ----
// Block = 256 thr / 4 waves (stacked in M).  Block owns ONE W-quarter
// (80 cols x 320 K = 51,200B LDS) staged once via global_load_lds + ONE
// __syncthreads; then ZERO barriers, ZERO in-loop staging.  Each wave:
// 64 rows x 80 cols per job; A-frags stream global->reg from the frag-major
// layout (perfectly coalesced 1KB loads, 1-step prefetch); B-frags ds_read
// from resident W.  Per K-step/wave: 4 gloads + 5 ds_reads + 20 MFMA (LDS
// serves ONLY B -> pipe floor ~17us).  3 blocks/CU (153KB LDS, bounds(256,3))
// gives 3 waves/SIMD TLP to hide A latency.  Block chains 4 row-tiles (1024
// rows) per W-residency; the 12 (mat,q) combos sharing an x-chunk are pinned
// to one XCD (L2-shared A).  Epilogue: SWAPPED-operand MFMA so lane holds 4
// consecutive cols -> u16x4 stores.
// W swizzle: 16B-chunk p of col at (p&~7)|((p&7)^(col&7)) (r11-measured 0
// bank conflicts; 2 lanes/slot on frag reads = free).
__global__ __launch_bounds__(256, 3) void k_gemm_all(
    const u16* __restrict__ x,  const u16* __restrict__ s2,
    const u16* __restrict__ s4, const u16* __restrict__ s10,
    const u16* __restrict__ s25,const u16* __restrict__ wT,
    u16* __restrict__ t0, u16* __restrict__ t1, u16* __restrict__ t2,
    u16* __restrict__ t3, u16* __restrict__ t4,
    u16* __restrict__ zb, u16* __restrict__ ob,
    const float* __restrict__ b_ce, const float* __restrict__ bz,
    const float* __restrict__ bo)
{
  __shared__ __align__(16) u16 W[25600];   // 51,200 B

  const int bid = blockIdx.x;
  int mat, q, c;
  if (bid < 768){                  // big-3: chunk c's 12 (mat,q) on one XCD
    const int g = bid / 96, rem = bid - g * 96;
    const int mq = rem >> 3, slot = rem & 7;
    c = g * 8 + slot; if (c >= 63) return;
    mat = mq >> 2; q = mq & 3;
  } else {
    int e = bid - 768;
    if (e < 128)      { mat = 3; q = e >> 5; c = e & 31; }
    else if (e < 192) { e -= 128; mat = 4; q = e >> 4; c = e & 15; }
    else if (e < 220) { e -= 192; mat = 5; q = e / 7;  c = e % 7; }
    else              { e -= 220; mat = 6; q = e / 3;  c = e % 3; }
  }

  const u16* A; u16* C; const float* bias; int mode; float scale; long Mrows; int wOff;
  switch (mat){
    case 0:  A = x;   C = t0; bias = b_ce;        mode = 0; scale = 1.f;   Mrows = 64000; wOff = 0; break;
    case 1:  A = x;   C = zb; bias = bz;          mode = 1; scale = 1.f;   Mrows = 64000; wOff = 5; break;
    case 2:  A = x;   C = ob; bias = bo;          mode = 1; scale = 1.f;   Mrows = 64000; wOff = 6; break;
    case 3:  A = s2;  C = t1; bias = b_ce + 300;  mode = 0; scale = 0.5f;  Mrows = 32000; wOff = 1; break;
    case 4:  A = s4;  C = t2; bias = b_ce + 600;  mode = 0; scale = 0.25f; Mrows = 16000; wOff = 2; break;
    case 5:  A = s10; C = t3; bias = b_ce + 900;  mode = 0; scale = 0.1f;  Mrows = 6400;  wOff = 3; break;
    default: A = s25; C = t4; bias = b_ce + 1200; mode = 0; scale = 0.04f; Mrows = 2560;  wOff = 4; break;
  }

  const int tid  = threadIdx.x;
  const int lane = tid & 63;
  const int wid  = tid >> 6;
  const int L    = lane & 15;
  const int kc   = lane >> 4;

  // ---- stage W-quarter once (3200 16B-chunks) ----
  {
    const u16* Wq = wT + wOff * 102400 + q * 80 * 320;
    const int wbase16 = wid * 1024;
    #pragma unroll
    for (int i = 0; i < 13; i++){
      const int ch = i * 256 + tid;
      if (ch < 3200){
        const int col = ch / 40, p = ch - col * 40;
        const int ps = (p & ~7) | ((p & 7) ^ (col & 7));
        gload16(Wq + col * 320 + ps * 8, (char*)W + i * 4096 + wbase16);
      }
    }
  }
  __syncthreads();                 // the ONLY barrier

  // ---- 4 chained jobs: 256 rows each (wave slice 64 rows x 80 cols) ----
  #pragma unroll 1
  for (int j2 = 0; j2 < 4; j2++){
    const long rowBase = (long)c * 1024 + j2 * 256 + wid * 64;
    if (rowBase >= Mrows) continue;           // Mrows % 64 == 0 for all mats
    const int mt0 = (int)(rowBase >> 4);

    floatx4 acc[4][5];
    #pragma unroll
    for (int m = 0; m < 4; m++)
      #pragma unroll
      for (int n = 0; n < 5; n++)
        #pragma unroll
        for (int z2 = 0; z2 < 4; z2++) acc[m][n][z2] = 0.f;

    short8 ca[4], na[4];
    #pragma unroll
    for (int m = 0; m < 4; m++)
      ca[m] = *(const short8*)(A + (size_t)((mt0 + m) * 10) * 512 + lane * 8);

    #pragma unroll
    for (int t = 0; t < 10; t++){
      if (t < 9){
        #pragma unroll
        for (int m = 0; m < 4; m++)
          na[m] = *(const short8*)(A + (size_t)((mt0 + m) * 10 + t + 1) * 512 + lane * 8);
      }
      short8 bf[5];
      #pragma unroll
      for (int n = 0; n < 5; n++){
        const int cl = n * 16 + L;
        bf[n] = *(const short8*)((const char*)W + cl * 640 + (((t * 4 + kc) ^ (cl & 7)) << 4));
      }
      #pragma unroll
      for (int m = 0; m < 4; m++)
        #pragma unroll
        for (int n = 0; n < 5; n++)   // SWAPPED operands: lane -> 4 consecutive cols
          acc[m][n] = __builtin_amdgcn_mfma_f32_16x16x32_bf16(bf[n], ca[m], acc[m][n], 0, 0, 0);
      #pragma unroll
      for (int m = 0; m < 4; m++) ca[m] = na[m];
    }

    // ---- epilogue: lane L = row-in-frag, kc*4+reg = col-in-frag ----
    #pragma unroll
    for (int n = 0; n < 5; n++){
      const int gcolq = q * 80 + n * 16 + kc * 4;
      if (gcolq < 300){
        const float4 bv4 = *(const float4*)(bias + gcolq);
        #pragma unroll
        for (int m = 0; m < 4; m++){
          const long grow = rowBase + m * 16 + L;
          u16x4 st;
          #pragma unroll
          for (int r = 0; r < 4; r++){
            float v = acc[m][n][r];
            const float bv = ((const float*)&bv4)[r];
            v = (mode == 0) ? (fmaxf(v, 0.f) + bv) * scale : tanh_fast(v) + bv;
            st[r] = f2bf(v);
          }
          *(u16x4*)(C + (size_t)grow * 300 + gcolq) = st;
        }
      }
    }
  }
}

// ---------------- gate MLP helper -------------------------------------------
__device__ __forceinline__ float gate_eval(
    float p0, float p1, float p2, float p3, float p4,
    const float W1[3][5], const float W2[3], const float B1[3], float B2)
{
  float acc2 = B2;
  #pragma unroll
  for (int t = 0; t < 3; t++){
    float u = W1[t][0]*p0 + W1[t][1]*p1 + W1[t][2]*p2 + W1[t][3]*p3 + W1[t][4]*p4 + B1[t];
    acc2 += W2[t] * fmaxf(u, 0.f);
  }
  return fmaxf(acc2, 0.f);
}

// ---------------- S1: per-chunk scan composites (40 chunks of 25) -----------
__global__ void k_scan1(const u16* __restrict__ t0, const u16* __restrict__ t1,
    const u16* __restrict__ t2, const u16* __restrict__ t3, const u16* __restrict__ t4,
    const u16* __restrict__ z,
    const float* __restrict__ w1, const float* __restrict__ b1,
    const float* __restrict__ w2, const float* __restrict__ b2,
    float* __restrict__ cA, float* __restrict__ cB, int total)
{
  int i = blockIdx.x * blockDim.x + threadIdx.x;
  if (i >= total) return;
  int d4 = i % 75; int rest = i / 75; int ch = rest % 40; int b = rest / 40;
  const int d = d4 * 4;
  float W1[3][5], W2[3], B1[3][4], B2[4];
  #pragma unroll
  for (int t = 0; t < 3; t++){
    #pragma unroll
    for (int s = 0; s < 5; s++) W1[t][s] = w1[t * 5 + s];
    W2[t] = w2[t];
    #pragma unroll
    for (int q = 0; q < 4; q++) B1[t][q] = b1[t * 300 + d + q];
  }
  #pragma unroll
  for (int q = 0; q < 4; q++) B2[q] = b2[d + q];
  float Ac[4] = {1.f,1.f,1.f,1.f}, Bc[4] = {0.f,0.f,0.f,0.f};
  const int l0 = ch * 25;
  const u16x4 v4 = *(const u16x4*)(t4 + (size_t)(b * 40 + ch) * 300 + d);  // l/25 == ch
  for (int l = l0; l < l0 + 25; l++){
    u16x4 v0 = *(const u16x4*)(t0 + (size_t)(b * 1000 + l)        * 300 + d);
    u16x4 v1 = *(const u16x4*)(t1 + (size_t)(b * 500  + (l >> 1)) * 300 + d);
    u16x4 v2 = *(const u16x4*)(t2 + (size_t)(b * 250  + (l >> 2)) * 300 + d);
    u16x4 v3 = *(const u16x4*)(t3 + (size_t)(b * 100  + l / 10)   * 300 + d);
    u16x4 vz = *(const u16x4*)(z  + (size_t)(b * 1000 + l)        * 300 + d);
    #pragma unroll
    for (int q = 0; q < 4; q++){
      float B1q[3] = {B1[0][q], B1[1][q], B1[2][q]};
      float g  = gate_eval(bf2f(v0[q]), bf2f(v1[q]), bf2f(v2[q]), bf2f(v3[q]), bf2f(v4[q]),
                           W1, W2, B1q, B2[q]);
      Ac[q] = g * Ac[q];
      Bc[q] = g * Bc[q] + (1.f - g) * bf2f(vz[q]);
    }
  }
  *(float4*)(cA + (size_t)ch * 19200 + b * 300 + d) = make_float4(Ac[0], Ac[1], Ac[2], Ac[3]);
  *(float4*)(cB + (size_t)ch * 19200 + b * 300 + d) = make_float4(Bc[0], Bc[1], Bc[2], Bc[3]);
}

// ---------------- S2: combine 40 chunk composites -> chunk-initial c --------
__global__ void k_scan2(const float* __restrict__ cA, const float* __restrict__ cB,
                        float* __restrict__ cinit, int total){
  int i = blockIdx.x * blockDim.x + threadIdx.x;
  if (i >= total) return;
  float c = 0.f;
  for (int ch = 0; ch < 40; ch++){
    cinit[ch * 19200 + i] = c;
    c = cA[ch * 19200 + i] * c + cB[ch * 19200 + i];
  }
}

// ---------------- S3: final scan + output h = o*c ---------------------------
__global__ void k_scan3(const u16* __restrict__ t0, const u16* __restrict__ t1,
    const u16* __restrict__ t2, const u16* __restrict__ t3, const u16* __restrict__ t4,
    const u16* __restrict__ z, const u16* __restrict__ o,
    const float* __restrict__ cinit,
    const float* __restrict__ w1, const float* __restrict__ b1,
    const float* __restrict__ w2, const float* __restrict__ b2,
    float* __restrict__ out, int total)
{
  int i = blockIdx.x * blockDim.x + threadIdx.x;
  if (i >= total) return;
  int d4 = i % 75; int rest = i / 75; int ch = rest % 40; int b = rest / 40;
  const int d = d4 * 4;
  float W1[3][5], W2[3], B1[3][4], B2[4];
  #pragma unroll
  for (int t = 0; t < 3; t++){
    #pragma unroll
    for (int s = 0; s < 5; s++) W1[t][s] = w1[t * 5 + s];
    W2[t] = w2[t];
    #pragma unroll
    for (int q = 0; q < 4; q++) B1[t][q] = b1[t * 300 + d + q];
  }
  #pragma unroll
  for (int q = 0; q < 4; q++) B2[q] = b2[d + q];
  float c[4];
  {
    float4 ci = *(const float4*)(cinit + (size_t)ch * 19200 + b * 300 + d);
    c[0] = ci.x; c[1] = ci.y; c[2] = ci.z; c[3] = ci.w;
  }
  const int l0 = ch * 25;
  const u16x4 v4 = *(const u16x4*)(t4 + (size_t)(b * 40 + ch) * 300 + d);
  for (int l = l0; l < l0 + 25; l++){
    u16x4 v0 = *(const u16x4*)(t0 + (size_t)(b * 1000 + l)        * 300 + d);
    u16x4 v1 = *(const u16x4*)(t1 + (size_t)(b * 500  + (l >> 1)) * 300 + d);
    u16x4 v2 = *(const u16x4*)(t2 + (size_t)(b * 250  + (l >> 2)) * 300 + d);
    u16x4 v3 = *(const u16x4*)(t3 + (size_t)(b * 100  + l / 10)   * 300 + d);
    u16x4 vz = *(const u16x4*)(z  + (size_t)(b * 1000 + l)        * 300 + d);
    u16x4 vo = *(const u16x4*)(o  + (size_t)(b * 1000 + l)        * 300 + d);
    float4 res;
    #pragma unroll
    for (int q = 0; q < 4; q++){
      float B1q[3] = {B1[0][q], B1[1][q], B1[2][q]};
      float g  = gate_eval(bf2f(v0[q]), bf2f(v1[q]), bf2f(v2[q]), bf2f(v3[q]), bf2f(v4[q]),
                           W1, W2, B1q, B2[q]);
      c[q] = g * c[q] + (1.f - g) * bf2f(vz[q]);
      ((float*)&res)[q] = bf2f(vo[q]) * c[q];
    }
    *(float4*)(out + (size_t)(b * 1000 + l) * 300 + d) = res;
  }
}

extern "C" void kernel_launch(void* const* d_in, const int* in_sizes, int n_in,
                              void* d_out, int out_size, void* d_ws, size_t ws_size,
                              hipStream_t stream){
  const int*   article = (const int*)  d_in[0];
  const float* emb     = (const float*)d_in[1];
  const float* w_ce    = (const float*)d_in[2];
  const float* b_ce    = (const float*)d_in[3];
  const float* w1      = (const float*)d_in[4];
  const float* b1      = (const float*)d_in[5];
  const float* w2      = (const float*)d_in[6];
  const float* b2      = (const float*)d_in[7];
  const float* wz      = (const float*)d_in[8];
  const float* bz      = (const float*)d_in[9];
  const float* wo      = (const float*)d_in[10];
  const float* bo      = (const float*)d_in[11];
  float* out = (float*)d_out;
  char*  ws  = (char*)d_ws;

  // workspace layout (bytes, all 256-aligned)
  u16* x    = (u16*)(ws + 0UL);          // 64000x320 bf16  = 40,960,000 (frag-major)
  u16* s2   = (u16*)(ws + 40960000UL);   // 32000x320       = 20,480,000 (frag-major)
  u16* s4   = (u16*)(ws + 61440000UL);   // 16000x320       = 10,240,000 (frag-major)
  u16* s10  = (u16*)(ws + 71680000UL);   //  6400x320       =  4,096,000 (frag-major)
  u16* s25  = (u16*)(ws + 75776000UL);   //  2560x320       =  1,638,400 (frag-major)
  u16* wT   = (u16*)(ws + 77414400UL);   // 7x320x320       =  1,433,600
  u16* t0   = (u16*)(ws + 78848000UL);   // 64000x300       = 38,400,000
  u16* t1   = (u16*)(ws + 117248000UL);  // 32000x300       = 19,200,000
  u16* t2   = (u16*)(ws + 136448000UL);  // 16000x300       =  9,600,000
  u16* t3   = (u16*)(ws + 146048000UL);  //  6400x300       =  3,840,000
  u16* t4   = (u16*)(ws + 149888000UL);  //  2560x300       =  1,536,000
  u16* zb   = (u16*)(ws + 151424000UL);  // 64000x300       = 38,400,000
  u16* ob   = (u16*)(ws + 189824000UL);  // 64000x300       = 38,400,000
  // scan composites live in the s2 region (dead after k_gemm_all):
  float* cA = (float*)(ws + 40960000UL); // 40x19200 f32 = 3,072,000
  float* cB = (float*)(ws + 44032000UL);
  float* ci = (float*)(ws + 47104000UL);
  (void)ws_size; (void)in_sizes; (void)n_in; (void)out_size;

  k_wprep     <<<2800, 256, 0, stream>>>(w_ce, wz, wo, wT, 716800);
  k_gather_seg<<<1000, 256, 0, stream>>>(article, emb, x, s2, s4, s10, 256000);
  k_s25       <<< 800, 256, 0, stream>>>(x, s25, 204800);

  k_gemm_all<<<1000, 256, 0, stream>>>(x, s2, s4, s10, s25, wT,
                                       t0, t1, t2, t3, t4, zb, ob,
                                       b_ce, bz, bo);

  k_scan1<<<750, 256, 0, stream>>>(t0, t1, t2, t3, t4, zb, w1, b1, w2, b2, cA, cB, 192000);
  k_scan2<<< 75, 256, 0, stream>>>(cA, cB, ci, 19200);
  k_scan3<<<750, 256, 0, stream>>>(t0, t1, t2, t3, t4, zb, ob, ci, w1, b1, w2, b2, out, 192000);
}

// Round 13
// 255.133 us; speedup vs baseline: 1.1883x; 1.1883x over previous
//
#include <hip/hip_runtime.h>
#include <hip/hip_bf16.h>

typedef unsigned short u16;
typedef unsigned int   u32;
typedef __attribute__((ext_vector_type(8))) short short8;
typedef __attribute__((ext_vector_type(4))) float floatx4;
typedef __attribute__((ext_vector_type(4))) unsigned short u16x4;

__device__ __forceinline__ u16 f2bf(float f){
  u32 x = __float_as_uint(f);
  u32 r = (x + 0x7fffu + ((x >> 16) & 1u)) >> 16;   // RNE
  return (u16)r;
}
__device__ __forceinline__ float bf2f(u16 u){
  return __uint_as_float(((u32)u) << 16);
}
// fast tanh: (e-1)/(e+1), e = 2^(2x*log2e). |err| < ~1e-5, invisible in bf16.
__device__ __forceinline__ float tanh_fast(float x){
  float xs = fminf(fmaxf(x, -16.f), 16.f);
  float e  = __builtin_amdgcn_exp2f(xs * 2.8853900817779268f);
  return (e - 1.f) * __builtin_amdgcn_rcpf(e + 1.f);
}
// async global->LDS, 16B per lane; LDS dest is wave-uniform base + lane*16
__device__ __forceinline__ void gload16(const void* g, void* l){
  __builtin_amdgcn_global_load_lds(
      (const __attribute__((address_space(1))) unsigned int*)g,
      (__attribute__((address_space(3))) unsigned int*)l, 16, 0, 0);
}

// B=64, L=1000, D=300 padded to 320; V=50000
// ---------------- K1: FUSED gather + bf16 cast + s2/s4/s10 segment sums -----
__global__ void k_gather_seg(const int* __restrict__ idx, const float* __restrict__ emb,
                             u16* __restrict__ x, u16* __restrict__ s2,
                             u16* __restrict__ s4, u16* __restrict__ s10, int total){
  int i = blockIdx.x * blockDim.x + threadIdx.x;
  if (i >= total) return;
  int d4 = i % 80; int rest = i / 80; int w = rest % 50; int b = rest / 50;
  const int dcol = d4 * 4;
  const int r0 = b * 1000 + w * 20;
  float a2[4] = {0,0,0,0}, a4[4] = {0,0,0,0}, a10[4] = {0,0,0,0};
  #pragma unroll
  for (int j = 0; j < 20; j++){
    const int r = r0 + j;
    u16x4 o; o[0] = 0; o[1] = 0; o[2] = 0; o[3] = 0;
    if (d4 < 75){
      const float4 v = *(const float4*)(emb + (size_t)idx[r] * 300 + dcol);
      o[0] = f2bf(v.x); o[1] = f2bf(v.y); o[2] = f2bf(v.z); o[3] = f2bf(v.w);
      a2[0] += v.x; a2[1] += v.y; a2[2] += v.z; a2[3] += v.w;
      a4[0] += v.x; a4[1] += v.y; a4[2] += v.z; a4[3] += v.w;
      a10[0] += v.x; a10[1] += v.y; a10[2] += v.z; a10[3] += v.w;
    }
    *(u16x4*)(x + (size_t)r * 320 + dcol) = o;
    if (j & 1){
      u16x4 s;
      #pragma unroll
      for (int q = 0; q < 4; q++){ s[q] = f2bf(a2[q]); a2[q] = 0.f; }
      *(u16x4*)(s2 + ((size_t)(b * 500 + w * 10 + (j >> 1)) * 320 + dcol)) = s;
    }
    if ((j & 3) == 3){
      u16x4 s;
      #pragma unroll
      for (int q = 0; q < 4; q++){ s[q] = f2bf(a4[q]); a4[q] = 0.f; }
      *(u16x4*)(s4 + ((size_t)(b * 250 + w * 5 + (j >> 2)) * 320 + dcol)) = s;
    }
    if (j == 9 || j == 19){
      u16x4 s;
      #pragma unroll
      for (int q = 0; q < 4; q++){ s[q] = f2bf(a10[q]); a10[q] = 0.f; }
      *(u16x4*)(s10 + ((size_t)(b * 100 + w * 2 + j / 10) * 320 + dcol)) = s;
    }
  }
}

// ---------------- K2: s25 from x --------------------------------------------
__global__ void k_s25(const u16* __restrict__ x, u16* __restrict__ s25, int total){
  int i = blockIdx.x * blockDim.x + threadIdx.x;
  if (i >= total) return;
  int d4 = i % 80; int rest = i / 80; int g = rest % 40; int b = rest / 40;
  const int dcol = d4 * 4;
  const u16* src = x + ((size_t)(b * 1000 + g * 25) * 320 + dcol);
  float a[4] = {0,0,0,0};
  #pragma unroll
  for (int j = 0; j < 25; j++){
    u16x4 v = *(const u16x4*)(src + (size_t)j * 320);
    #pragma unroll
    for (int q = 0; q < 4; q++) a[q] += bf2f(v[q]);
  }
  u16x4 o;
  #pragma unroll
  for (int q = 0; q < 4; q++) o[q] = f2bf(a[q]);
  *(u16x4*)(s25 + ((size_t)(b * 40 + g) * 320 + dcol)) = o;
}

// ---------------- K3: pack weights transposed+padded: wT[mat][n*320+k] ------
__global__ void k_wprep(const float* __restrict__ wce, const float* __restrict__ wz,
                        const float* __restrict__ wo, u16* __restrict__ wT, int total){
  int i = blockIdx.x * blockDim.x + threadIdx.x;
  if (i >= total) return;
  int mat = i / 102400; int rem = i - mat * 102400;
  int n = rem / 320;    int k = rem - n * 320;
  float v = 0.f;
  if (n < 300 && k < 300){
    const float* src = (mat < 5) ? (wce + mat * 90000) : (mat == 5 ? wz : wo);
    v = src[k * 300 + n];
  }
  wT[i] = f2bf(v);
}

// ---------------- K4: ALL GEMMs — r6 geometry + TRUE counted-vmcnt (T3+T4) --
// r6 shell (256 thr / 4 waves N-split, tile 64x320, K-step 32, uniform
// 6 gload_lds per thread per tile, 0-conflict swizzles, VGPR ~76-88).
// NEW vs r6: 3 LDS buffers (24KB x3 = 72KB, 2 blocks/CU), 2-tiles-ahead
// prefetch, raw s_barrier + s_waitcnt vmcnt(6) — tile t+1 stays IN FLIGHT
// across the barrier; no vmcnt(0) drain in the main loop.  vs r8: NO
// sched_barrier(0) (m141: that pin alone costs ~-40%, matching r8's loss).
// Accounting: at iter-t top outstanding = tiles t,t+1 = 12 loads ->
// vmcnt(6) == tile t landed.  stage(t+2) goes right after the barrier:
// buffer (t+2)%3 == (t-1)%3 and the barrier proves all waves left t-1.
__global__ __launch_bounds__(256, 3) void k_gemm_all(
    const u16* __restrict__ x,  const u16* __restrict__ s2,
    const u16* __restrict__ s4, const u16* __restrict__ s10,
    const u16* __restrict__ s25,const u16* __restrict__ wT,
    u16* __restrict__ t0, u16* __restrict__ t1, u16* __restrict__ t2,
    u16* __restrict__ t3, u16* __restrict__ t4,
    u16* __restrict__ zb, u16* __restrict__ ob,
    const float* __restrict__ b_ce, const float* __restrict__ bz,
    const float* __restrict__ bo)
{
  // 3 buffers x [A:4096][B:20480] = 73728 B
  __shared__ __align__(16) char lds[73728];

  const int bid = blockIdx.x;
  const u16 *A, *BT; u16* C; const float* bias;
  int mode; float scale; long tileRow;
  if (bid < 3000){                 // t0/z/o trios, XCD-grouped (x L2-shared)
    const int xcd = bid & 7, j = bid >> 3;   // j in [0,375)
    const int T = (j / 3) * 8 + xcd, m = j % 3;  // T in [0,1000)
    tileRow = (long)T * 64; A = x;
    if (m == 0)      { BT = wT;              C = t0; bias = b_ce; mode = 0; scale = 1.f; }
    else if (m == 1) { BT = wT + 5 * 102400; C = zb; bias = bz;   mode = 1; scale = 1.f; }
    else             { BT = wT + 6 * 102400; C = ob; bias = bo;   mode = 1; scale = 1.f; }
  } else {
    const int g = bid - 3000;
    if (g < 500)      { A=s2;  BT=wT+1*102400; C=t1; bias=b_ce+300;  mode=0; scale=0.5f;  tileRow=(long)g*64; }
    else if (g < 750) { A=s4;  BT=wT+2*102400; C=t2; bias=b_ce+600;  mode=0; scale=0.25f; tileRow=(long)(g-500)*64; }
    else if (g < 850) { A=s10; BT=wT+3*102400; C=t3; bias=b_ce+900;  mode=0; scale=0.1f;  tileRow=(long)(g-750)*64; }
    else              { A=s25; BT=wT+4*102400; C=t4; bias=b_ce+1200; mode=0; scale=0.04f; tileRow=(long)(g-850)*64; }
  }

  const int tid  = threadIdx.x;
  const int lane = tid & 63;
  const int wid  = tid >> 6;      // 0..3 = N-wave

  // ---- staging sources (pre-swizzled chunk within each row's 64B) ----
  const int arow = tid >> 2, ac = tid & 3;
  const u16* aSrc = A + (tileRow + arow) * 320 + ((ac ^ ((arow >> 1) & 3)) << 3);
  const u16* bSrc[5];
  #pragma unroll
  for (int l = 0; l < 5; l++){
    const int idx2 = l * 256 + tid, col = idx2 >> 2, cc = idx2 & 3;
    bSrc[l] = BT + col * 320 + ((cc ^ ((col >> 1) & 3)) << 3);
  }
  const int wbase = wid * 1024;   // wave-uniform LDS dest base (+lane*16 by HW)

  // ---- frag read offsets (matching XOR) ----
  const int rA  = lane & 15;
  const int cBt = wid * 80 + (lane & 15);
  const int kchunk = ((lane >> 4) ^ ((lane >> 1) & 3)) << 4;

  floatx4 acc[4][5];
  #pragma unroll
  for (int m = 0; m < 4; m++)
    #pragma unroll
    for (int n = 0; n < 5; n++)
      #pragma unroll
      for (int q = 0; q < 4; q++) acc[m][n][q] = 0.f;

  // stage tile t into buffer nb: 6 gloads per thread (1 A + 5 B), uniform
  #define STAGE(t, nb) do {                                                   \
    gload16(aSrc + (t) * 32, lds + (nb) * 24576 + wbase);                     \
    _Pragma("unroll")                                                         \
    for (int l = 0; l < 5; l++)                                               \
      gload16(bSrc[l] + (t) * 32, lds + (nb) * 24576 + 4096 + l * 4096 + wbase); \
  } while (0)

  // prologue: tiles 0,1 in flight (outstanding = 12)
  STAGE(0, 0);
  STAGE(1, 1);

  #pragma unroll
  for (int t = 0; t < 10; t++){
    if (t < 9) asm volatile("s_waitcnt vmcnt(6)" ::: "memory");  // tile t landed; t+1 in flight
    else       asm volatile("s_waitcnt vmcnt(0)" ::: "memory");
    __builtin_amdgcn_s_barrier();        // all waves' tile-t DMA visible
    if (t < 8) STAGE(t + 2, (t + 2) % 3);   // buffer (t-1)%3 is free (barrier above)
    const char* Ab = lds + (t % 3) * 24576;
    const char* Bb = Ab + 4096;
    short8 af[4], bf[5];
    #pragma unroll
    for (int m = 0; m < 4; m++)
      af[m] = *(const short8*)(Ab + (rA + m * 16) * 64 + kchunk);
    #pragma unroll
    for (int n = 0; n < 5; n++)
      bf[n] = *(const short8*)(Bb + (cBt + n * 16) * 64 + kchunk);
    #pragma unroll
    for (int m = 0; m < 4; m++)
      #pragma unroll
      for (int n = 0; n < 5; n++)
        acc[m][n] = __builtin_amdgcn_mfma_f32_16x16x32_bf16(af[m], bf[n], acc[m][n], 0, 0, 0);
  }
  #undef STAGE

  // ---- epilogue: D[row][col]: col = lane&15, row = (lane>>4)*4 + reg ----
  const int colbase = wid * 80 + (lane & 15);
  const long rowb   = tileRow + ((lane >> 4) << 2);
  #pragma unroll
  for (int m = 0; m < 4; m++){
    #pragma unroll
    for (int n = 0; n < 5; n++){
      const int gcol = colbase + n * 16;
      if (gcol < 300){
        const float bv = bias[gcol];
        #pragma unroll
        for (int r = 0; r < 4; r++){
          const long grow = rowb + m * 16 + r;
          float v = acc[m][n][r];
          v = (mode == 0) ? (fmaxf(v, 0.f) + bv) * scale : tanh_fast(v) + bv;
          C[grow * 300 + gcol] = f2bf(v);
        }
      }
    }
  }
}

// ---------------- gate MLP helper -------------------------------------------
__device__ __forceinline__ float gate_eval(
    float p0, float p1, float p2, float p3, float p4,
    const float W1[3][5], const float W2[3], const float B1[3], float B2)
{
  float acc2 = B2;
  #pragma unroll
  for (int t = 0; t < 3; t++){
    float u = W1[t][0]*p0 + W1[t][1]*p1 + W1[t][2]*p2 + W1[t][3]*p3 + W1[t][4]*p4 + B1[t];
    acc2 += W2[t] * fmaxf(u, 0.f);
  }
  return fmaxf(acc2, 0.f);
}

// ---------------- S1: per-chunk scan composites (40 chunks of 25) -----------
__global__ void k_scan1(const u16* __restrict__ t0, const u16* __restrict__ t1,
    const u16* __restrict__ t2, const u16* __restrict__ t3, const u16* __restrict__ t4,
    const u16* __restrict__ z,
    const float* __restrict__ w1, const float* __restrict__ b1,
    const float* __restrict__ w2, const float* __restrict__ b2,
    float* __restrict__ cA, float* __restrict__ cB, int total)
{
  int i = blockIdx.x * blockDim.x + threadIdx.x;
  if (i >= total) return;
  int d4 = i % 75; int rest = i / 75; int ch = rest % 40; int b = rest / 40;
  const int d = d4 * 4;
  float W1[3][5], W2[3], B1[3][4], B2[4];
  #pragma unroll
  for (int t = 0; t < 3; t++){
    #pragma unroll
    for (int s = 0; s < 5; s++) W1[t][s] = w1[t * 5 + s];
    W2[t] = w2[t];
    #pragma unroll
    for (int q = 0; q < 4; q++) B1[t][q] = b1[t * 300 + d + q];
  }
  #pragma unroll
  for (int q = 0; q < 4; q++) B2[q] = b2[d + q];
  float Ac[4] = {1.f,1.f,1.f,1.f}, Bc[4] = {0.f,0.f,0.f,0.f};
  const int l0 = ch * 25;
  const u16x4 v4 = *(const u16x4*)(t4 + (size_t)(b * 40 + ch) * 300 + d);  // l/25 == ch
  for (int l = l0; l < l0 + 25; l++){
    u16x4 v0 = *(const u16x4*)(t0 + (size_t)(b * 1000 + l)        * 300 + d);
    u16x4 v1 = *(const u16x4*)(t1 + (size_t)(b * 500  + (l >> 1)) * 300 + d);
    u16x4 v2 = *(const u16x4*)(t2 + (size_t)(b * 250  + (l >> 2)) * 300 + d);
    u16x4 v3 = *(const u16x4*)(t3 + (size_t)(b * 100  + l / 10)   * 300 + d);
    u16x4 vz = *(const u16x4*)(z  + (size_t)(b * 1000 + l)        * 300 + d);
    #pragma unroll
    for (int q = 0; q < 4; q++){
      float B1q[3] = {B1[0][q], B1[1][q], B1[2][q]};
      float g  = gate_eval(bf2f(v0[q]), bf2f(v1[q]), bf2f(v2[q]), bf2f(v3[q]), bf2f(v4[q]),
                           W1, W2, B1q, B2[q]);
      Ac[q] = g * Ac[q];
      Bc[q] = g * Bc[q] + (1.f - g) * bf2f(vz[q]);
    }
  }
  *(float4*)(cA + (size_t)ch * 19200 + b * 300 + d) = make_float4(Ac[0], Ac[1], Ac[2], Ac[3]);
  *(float4*)(cB + (size_t)ch * 19200 + b * 300 + d) = make_float4(Bc[0], Bc[1], Bc[2], Bc[3]);
}

// ---------------- S2: combine 40 chunk composites -> chunk-initial c --------
__global__ void k_scan2(const float* __restrict__ cA, const float* __restrict__ cB,
                        float* __restrict__ cinit, int total){
  int i = blockIdx.x * blockDim.x + threadIdx.x;
  if (i >= total) return;
  float c = 0.f;
  for (int ch = 0; ch < 40; ch++){
    cinit[ch * 19200 + i] = c;
    c = cA[ch * 19200 + i] * c + cB[ch * 19200 + i];
  }
}

// ---------------- S3: final scan + output h = o*c ---------------------------
__global__ void k_scan3(const u16* __restrict__ t0, const u16* __restrict__ t1,
    const u16* __restrict__ t2, const u16* __restrict__ t3, const u16* __restrict__ t4,
    const u16* __restrict__ z, const u16* __restrict__ o,
    const float* __restrict__ cinit,
    const float* __restrict__ w1, const float* __restrict__ b1,
    const float* __restrict__ w2, const float* __restrict__ b2,
    float* __restrict__ out, int total)
{
  int i = blockIdx.x * blockDim.x + threadIdx.x;
  if (i >= total) return;
  int d4 = i % 75; int rest = i / 75; int ch = rest % 40; int b = rest / 40;
  const int d = d4 * 4;
  float W1[3][5], W2[3], B1[3][4], B2[4];
  #pragma unroll
  for (int t = 0; t < 3; t++){
    #pragma unroll
    for (int s = 0; s < 5; s++) W1[t][s] = w1[t * 5 + s];
    W2[t] = w2[t];
    #pragma unroll
    for (int q = 0; q < 4; q++) B1[t][q] = b1[t * 300 + d + q];
  }
  #pragma unroll
  for (int q = 0; q < 4; q++) B2[q] = b2[d + q];
  float c[4];
  {
    float4 ci = *(const float4*)(cinit + (size_t)ch * 19200 + b * 300 + d);
    c[0] = ci.x; c[1] = ci.y; c[2] = ci.z; c[3] = ci.w;
  }
  const int l0 = ch * 25;
  const u16x4 v4 = *(const u16x4*)(t4 + (size_t)(b * 40 + ch) * 300 + d);
  for (int l = l0; l < l0 + 25; l++){
    u16x4 v0 = *(const u16x4*)(t0 + (size_t)(b * 1000 + l)        * 300 + d);
    u16x4 v1 = *(const u16x4*)(t1 + (size_t)(b * 500  + (l >> 1)) * 300 + d);
    u16x4 v2 = *(const u16x4*)(t2 + (size_t)(b * 250  + (l >> 2)) * 300 + d);
    u16x4 v3 = *(const u16x4*)(t3 + (size_t)(b * 100  + l / 10)   * 300 + d);
    u16x4 vz = *(const u16x4*)(z  + (size_t)(b * 1000 + l)        * 300 + d);
    u16x4 vo = *(const u16x4*)(o  + (size_t)(b * 1000 + l)        * 300 + d);
    float4 res;
    #pragma unroll
    for (int q = 0; q < 4; q++){
      float B1q[3] = {B1[0][q], B1[1][q], B1[2][q]};
      float g  = gate_eval(bf2f(v0[q]), bf2f(v1[q]), bf2f(v2[q]), bf2f(v3[q]), bf2f(v4[q]),
                           W1, W2, B1q, B2[q]);
      c[q] = g * c[q] + (1.f - g) * bf2f(vz[q]);
      ((float*)&res)[q] = bf2f(vo[q]) * c[q];
    }
    *(float4*)(out + (size_t)(b * 1000 + l) * 300 + d) = res;
  }
}

extern "C" void kernel_launch(void* const* d_in, const int* in_sizes, int n_in,
                              void* d_out, int out_size, void* d_ws, size_t ws_size,
                              hipStream_t stream){
  const int*   article = (const int*)  d_in[0];
  const float* emb     = (const float*)d_in[1];
  const float* w_ce    = (const float*)d_in[2];
  const float* b_ce    = (const float*)d_in[3];
  const float* w1      = (const float*)d_in[4];
  const float* b1      = (const float*)d_in[5];
  const float* w2      = (const float*)d_in[6];
  const float* b2      = (const float*)d_in[7];
  const float* wz      = (const float*)d_in[8];
  const float* bz      = (const float*)d_in[9];
  const float* wo      = (const float*)d_in[10];
  const float* bo      = (const float*)d_in[11];
  float* out = (float*)d_out;
  char*  ws  = (char*)d_ws;

  // workspace layout (bytes, all 256-aligned)
  u16* x    = (u16*)(ws + 0UL);          // 64000x320 bf16  = 40,960,000
  u16* s2   = (u16*)(ws + 40960000UL);   // 32000x320       = 20,480,000
  u16* s4   = (u16*)(ws + 61440000UL);   // 16000x320       = 10,240,000
  u16* s10  = (u16*)(ws + 71680000UL);   //  6400x320       =  4,096,000
  u16* s25  = (u16*)(ws + 75776000UL);   //  2560x320       =  1,638,400
  u16* wT   = (u16*)(ws + 77414400UL);   // 7x320x320       =  1,433,600
  u16* t0   = (u16*)(ws + 78848000UL);   // 64000x300       = 38,400,000
  u16* t1   = (u16*)(ws + 117248000UL);  // 32000x300       = 19,200,000
  u16* t2   = (u16*)(ws + 136448000UL);  // 16000x300       =  9,600,000
  u16* t3   = (u16*)(ws + 146048000UL);  //  6400x300       =  3,840,000
  u16* t4   = (u16*)(ws + 149888000UL);  //  2560x300       =  1,536,000
  u16* zb   = (u16*)(ws + 151424000UL);  // 64000x300       = 38,400,000
  u16* ob   = (u16*)(ws + 189824000UL);  // 64000x300       = 38,400,000
  // scan composites live in the s2 region (dead after k_gemm_all):
  float* cA = (float*)(ws + 40960000UL); // 40x19200 f32 = 3,072,000
  float* cB = (float*)(ws + 44032000UL);
  float* ci = (float*)(ws + 47104000UL);
  (void)ws_size; (void)in_sizes; (void)n_in; (void)out_size;

  k_wprep     <<<2800, 256, 0, stream>>>(w_ce, wz, wo, wT, 716800);
  k_gather_seg<<<1000, 256, 0, stream>>>(article, emb, x, s2, s4, s10, 256000);
  k_s25       <<< 800, 256, 0, stream>>>(x, s25, 204800);

  k_gemm_all<<<3890, 256, 0, stream>>>(x, s2, s4, s10, s25, wT,
                                       t0, t1, t2, t3, t4, zb, ob,
                                       b_ce, bz, bo);

  k_scan1<<<750, 256, 0, stream>>>(t0, t1, t2, t3, t4, zb, w1, b1, w2, b2, cA, cB, 192000);
  k_scan2<<< 75, 256, 0, stream>>>(cA, cB, ci, 19200);
  k_scan3<<<750, 256, 0, stream>>>(t0, t1, t2, t3, t4, zb, ob, ci, w1, b1, w2, b2, out, 192000);
}

// Round 14
// 229.087 us; speedup vs baseline: 1.3234x; 1.1137x over previous
//
#include <hip/hip_runtime.h>
#include <hip/hip_bf16.h>

typedef unsigned short u16;
typedef unsigned int   u32;
typedef __attribute__((ext_vector_type(8))) short short8;
typedef __attribute__((ext_vector_type(4))) float floatx4;
typedef __attribute__((ext_vector_type(4))) unsigned short u16x4;

__device__ __forceinline__ u16 f2bf(float f){
  u32 x = __float_as_uint(f);
  u32 r = (x + 0x7fffu + ((x >> 16) & 1u)) >> 16;   // RNE
  return (u16)r;
}
__device__ __forceinline__ float bf2f(u16 u){
  return __uint_as_float(((u32)u) << 16);
}
// fast tanh: (e-1)/(e+1), e = 2^(2x*log2e). |err| < ~1e-5, invisible in bf16.
__device__ __forceinline__ float tanh_fast(float x){
  float xs = fminf(fmaxf(x, -16.f), 16.f);
  float e  = __builtin_amdgcn_exp2f(xs * 2.8853900817779268f);
  return (e - 1.f) * __builtin_amdgcn_rcpf(e + 1.f);
}
// async global->LDS, 16B per lane; LDS dest is wave-uniform base + lane*16
__device__ __forceinline__ void gload16(const void* g, void* l){
  __builtin_amdgcn_global_load_lds(
      (const __attribute__((address_space(1))) unsigned int*)g,
      (__attribute__((address_space(3))) unsigned int*)l, 16, 0, 0);
}

// B=64, L=1000, D=300 padded to 320; V=50000
// ---------------- K1: FUSED gather + bf16 cast + s2/s4/s10 segment sums -----
__global__ void k_gather_seg(const int* __restrict__ idx, const float* __restrict__ emb,
                             u16* __restrict__ x, u16* __restrict__ s2,
                             u16* __restrict__ s4, u16* __restrict__ s10, int total){
  int i = blockIdx.x * blockDim.x + threadIdx.x;
  if (i >= total) return;
  int d4 = i % 80; int rest = i / 80; int w = rest % 50; int b = rest / 50;
  const int dcol = d4 * 4;
  const int r0 = b * 1000 + w * 20;
  float a2[4] = {0,0,0,0}, a4[4] = {0,0,0,0}, a10[4] = {0,0,0,0};
  #pragma unroll
  for (int j = 0; j < 20; j++){
    const int r = r0 + j;
    u16x4 o; o[0] = 0; o[1] = 0; o[2] = 0; o[3] = 0;
    if (d4 < 75){
      const float4 v = *(const float4*)(emb + (size_t)idx[r] * 300 + dcol);
      o[0] = f2bf(v.x); o[1] = f2bf(v.y); o[2] = f2bf(v.z); o[3] = f2bf(v.w);
      a2[0] += v.x; a2[1] += v.y; a2[2] += v.z; a2[3] += v.w;
      a4[0] += v.x; a4[1] += v.y; a4[2] += v.z; a4[3] += v.w;
      a10[0] += v.x; a10[1] += v.y; a10[2] += v.z; a10[3] += v.w;
    }
    *(u16x4*)(x + (size_t)r * 320 + dcol) = o;
    if (j & 1){
      u16x4 s;
      #pragma unroll
      for (int q = 0; q < 4; q++){ s[q] = f2bf(a2[q]); a2[q] = 0.f; }
      *(u16x4*)(s2 + ((size_t)(b * 500 + w * 10 + (j >> 1)) * 320 + dcol)) = s;
    }
    if ((j & 3) == 3){
      u16x4 s;
      #pragma unroll
      for (int q = 0; q < 4; q++){ s[q] = f2bf(a4[q]); a4[q] = 0.f; }
      *(u16x4*)(s4 + ((size_t)(b * 250 + w * 5 + (j >> 2)) * 320 + dcol)) = s;
    }
    if (j == 9 || j == 19){
      u16x4 s;
      #pragma unroll
      for (int q = 0; q < 4; q++){ s[q] = f2bf(a10[q]); a10[q] = 0.f; }
      *(u16x4*)(s10 + ((size_t)(b * 100 + w * 2 + j / 10) * 320 + dcol)) = s;
    }
  }
}

// ---------------- K2: s25 from x --------------------------------------------
__global__ void k_s25(const u16* __restrict__ x, u16* __restrict__ s25, int total){
  int i = blockIdx.x * blockDim.x + threadIdx.x;
  if (i >= total) return;
  int d4 = i % 80; int rest = i / 80; int g = rest % 40; int b = rest / 40;
  const int dcol = d4 * 4;
  const u16* src = x + ((size_t)(b * 1000 + g * 25) * 320 + dcol);
  float a[4] = {0,0,0,0};
  #pragma unroll
  for (int j = 0; j < 25; j++){
    u16x4 v = *(const u16x4*)(src + (size_t)j * 320);
    #pragma unroll
    for (int q = 0; q < 4; q++) a[q] += bf2f(v[q]);
  }
  u16x4 o;
  #pragma unroll
  for (int q = 0; q < 4; q++) o[q] = f2bf(a[q]);
  *(u16x4*)(s25 + ((size_t)(b * 40 + g) * 320 + dcol)) = o;
}

// ---------------- K3: pack weights transposed+padded: wT[mat][n*320+k] ------
__global__ void k_wprep(const float* __restrict__ wce, const float* __restrict__ wz,
                        const float* __restrict__ wo, u16* __restrict__ wT, int total){
  int i = blockIdx.x * blockDim.x + threadIdx.x;
  if (i >= total) return;
  int mat = i / 102400; int rem = i - mat * 102400;
  int n = rem / 320;    int k = rem - n * 320;
  float v = 0.f;
  if (n < 300 && k < 300){
    const float* src = (mat < 5) ? (wce + mat * 90000) : (mat == 5 ? wz : wo);
    v = src[k * 300 + n];
  }
  wT[i] = f2bf(v);
}

// ---------------- K4: ALL GEMMs — r5 shell (best measured) + vec epilogue ---
// C[M,300] = post(A[M,320] @ W).  Block = 512 thr (8 waves 2Mx4N), tile
// 128x320, K-step 64 (5 iters), LDS 114KB double-buffered (1 block/CU) —
// the best-measured GEMM config (r5: 103us).  Staging via global_load_lds
// w=16, linear LDS dest + inverse-swizzled global source (rule 21), chunk
// swizzle c^(row&7) on 128B rows (r5-measured 0 bank conflicts).
// NEW (r12-verified): SWAPPED-operand MFMA — mfma(bf, af, acc) puts 4
// consecutive output COLS in each lane's 4 acc regs -> u16x4 C-stores
// (80 scalar stores/thread -> 20 vector stores).
__global__ __launch_bounds__(512, 2) void k_gemm_all(
    const u16* __restrict__ x,  const u16* __restrict__ s2,
    const u16* __restrict__ s4, const u16* __restrict__ s10,
    const u16* __restrict__ s25,const u16* __restrict__ wT,
    u16* __restrict__ t0, u16* __restrict__ t1, u16* __restrict__ t2,
    u16* __restrict__ t3, u16* __restrict__ t4,
    u16* __restrict__ zb, u16* __restrict__ ob,
    const float* __restrict__ b_ce, const float* __restrict__ bz,
    const float* __restrict__ bo)
{
  // [A0:16384][A1:16384][B0:40960][B1:40960] = 114688 B
  __shared__ __align__(16) char lds[114688];

  const int bid = blockIdx.x;
  const u16 *A, *BT; u16* C; const float* bias;
  int mode; float scale; long tileRow;
  if (bid < 1512){                 // t0/z/o trios, XCD-grouped (x L2-shared)
    const int xcd = bid & 7, j = bid >> 3;
    const int T = (j / 3) * 8 + xcd, m = j % 3;
    if (T >= 500) return;
    tileRow = (long)T * 128; A = x;
    if (m == 0)      { BT = wT;              C = t0; bias = b_ce; mode = 0; scale = 1.f; }
    else if (m == 1) { BT = wT + 5 * 102400; C = zb; bias = bz;   mode = 1; scale = 1.f; }
    else             { BT = wT + 6 * 102400; C = ob; bias = bo;   mode = 1; scale = 1.f; }
  } else {
    const int g = bid - 1512;
    if (g < 250)      { A=s2;  BT=wT+1*102400; C=t1; bias=b_ce+300;  mode=0; scale=0.5f;  tileRow=(long)g*128; }
    else if (g < 375) { A=s4;  BT=wT+2*102400; C=t2; bias=b_ce+600;  mode=0; scale=0.25f; tileRow=(long)(g-250)*128; }
    else if (g < 425) { A=s10; BT=wT+3*102400; C=t3; bias=b_ce+900;  mode=0; scale=0.1f;  tileRow=(long)(g-375)*128; }
    else              { A=s25; BT=wT+4*102400; C=t4; bias=b_ce+1200; mode=0; scale=0.04f; tileRow=(long)(g-425)*128; }
  }

  const int tid  = threadIdx.x;
  const int lane = tid & 63;
  const int wid  = tid >> 6;
  const int wr   = wid >> 2;     // 0..1  (64-row half)
  const int wc   = wid & 3;      // 0..3  (80-col group)

  // ---- staging source addrs (pre-swizzled) + wave-uniform LDS dest offs ----
  // A tile: 128 rows x 8 chunks (chunk=16B=8 K-elems); idx = l*512+tid
  const u16* aSrc[2]; int aDst[2];
  #pragma unroll
  for (int l = 0; l < 2; l++){
    const int idx = l * 512 + tid, row = idx >> 3, c = idx & 7;
    aSrc[l] = A + (tileRow + row) * 320 + ((c ^ (row & 7)) << 3);
    aDst[l] = (l * 512 + wid * 64) * 16;
  }
  // B tile: 320 cols x 8 chunks
  const u16* bSrc[5]; int bDst[5];
  #pragma unroll
  for (int l = 0; l < 5; l++){
    const int idx = l * 512 + tid, col = idx >> 3, c = idx & 7;
    bSrc[l] = BT + col * 320 + ((c ^ (col & 7)) << 3);
    bDst[l] = (l * 512 + wid * 64) * 16;
  }

  // ---- frag read offsets (with matching XOR swizzle) ----
  const int rA  = wr * 64 + (lane & 15);      // row within A tile
  const int cBt = wc * 80 + (lane & 15);      // col within B tile
  int ksw[2];
  #pragma unroll
  for (int s = 0; s < 2; s++)
    ksw[s] = ((s * 4 + (lane >> 4)) ^ (lane & 7)) << 4;

  floatx4 acc[4][5];
  #pragma unroll
  for (int m = 0; m < 4; m++)
    #pragma unroll
    for (int n = 0; n < 5; n++)
      #pragma unroll
      for (int q = 0; q < 4; q++) acc[m][n][q] = 0.f;

  // ---- prologue: stage tile 0 ----
  #pragma unroll
  for (int l = 0; l < 2; l++) gload16(aSrc[l], lds + aDst[l]);
  #pragma unroll
  for (int l = 0; l < 5; l++) gload16(bSrc[l], lds + 32768 + bDst[l]);
  __syncthreads();

  #pragma unroll
  for (int t = 0; t < 5; t++){
    const int cur = t & 1;
    if (t < 4){                   // issue next-tile DMA into the other buffer
      const int nb = cur ^ 1;
      #pragma unroll
      for (int l = 0; l < 2; l++) gload16(aSrc[l] + (t + 1) * 64, lds + nb * 16384 + aDst[l]);
      #pragma unroll
      for (int l = 0; l < 5; l++) gload16(bSrc[l] + (t + 1) * 64, lds + 32768 + nb * 40960 + bDst[l]);
    }
    const char* bA = lds + cur * 16384;
    const char* bB = lds + 32768 + cur * 40960;
    #pragma unroll
    for (int s = 0; s < 2; s++){
      short8 af[4], bf[5];
      #pragma unroll
      for (int m = 0; m < 4; m++)
        af[m] = *(const short8*)(bA + (rA + m * 16) * 128 + ksw[s]);
      #pragma unroll
      for (int n = 0; n < 5; n++)
        bf[n] = *(const short8*)(bB + (cBt + n * 16) * 128 + ksw[s]);
      #pragma unroll
      for (int m = 0; m < 4; m++)
        #pragma unroll
        for (int n = 0; n < 5; n++)   // SWAPPED operands: lane -> 4 consecutive cols
          acc[m][n] = __builtin_amdgcn_mfma_f32_16x16x32_bf16(bf[n], af[m], acc[m][n], 0, 0, 0);
    }
    __syncthreads();              // drains vmcnt(0): stage(t+1) landed long ago
  }

  // ---- epilogue (swapped D): row = lane&15 (+m*16), col = (lane>>4)*4+reg --
  const int L  = lane & 15;
  const int kc = lane >> 4;
  const long rowb = tileRow + wr * 64 + L;
  #pragma unroll
  for (int n = 0; n < 5; n++){
    const int gcol = wc * 80 + n * 16 + kc * 4;   // 4-aligned; 300%4==0
    if (gcol < 300){
      const float4 bv4 = *(const float4*)(bias + gcol);
      #pragma unroll
      for (int m = 0; m < 4; m++){
        const long grow = rowb + m * 16;
        u16x4 st;
        #pragma unroll
        for (int r = 0; r < 4; r++){
          float v = acc[m][n][r];
          const float bv = ((const float*)&bv4)[r];
          v = (mode == 0) ? (fmaxf(v, 0.f) + bv) * scale : tanh_fast(v) + bv;
          st[r] = f2bf(v);
        }
        *(u16x4*)(C + (size_t)grow * 300 + gcol) = st;
      }
    }
  }
}

// ---------------- gate MLP helper -------------------------------------------
__device__ __forceinline__ float gate_eval(
    float p0, float p1, float p2, float p3, float p4,
    const float W1[3][5], const float W2[3], const float B1[3], float B2)
{
  float acc2 = B2;
  #pragma unroll
  for (int t = 0; t < 3; t++){
    float u = W1[t][0]*p0 + W1[t][1]*p1 + W1[t][2]*p2 + W1[t][3]*p3 + W1[t][4]*p4 + B1[t];
    acc2 += W2[t] * fmaxf(u, 0.f);
  }
  return fmaxf(acc2, 0.f);
}

// ---------------- S1: per-chunk scan composites (40 chunks of 25) -----------
__global__ void k_scan1(const u16* __restrict__ t0, const u16* __restrict__ t1,
    const u16* __restrict__ t2, const u16* __restrict__ t3, const u16* __restrict__ t4,
    const u16* __restrict__ z,
    const float* __restrict__ w1, const float* __restrict__ b1,
    const float* __restrict__ w2, const float* __restrict__ b2,
    float* __restrict__ cA, float* __restrict__ cB, int total)
{
  int i = blockIdx.x * blockDim.x + threadIdx.x;
  if (i >= total) return;
  int d4 = i % 75; int rest = i / 75; int ch = rest % 40; int b = rest / 40;
  const int d = d4 * 4;
  float W1[3][5], W2[3], B1[3][4], B2[4];
  #pragma unroll
  for (int t = 0; t < 3; t++){
    #pragma unroll
    for (int s = 0; s < 5; s++) W1[t][s] = w1[t * 5 + s];
    W2[t] = w2[t];
    #pragma unroll
    for (int q = 0; q < 4; q++) B1[t][q] = b1[t * 300 + d + q];
  }
  #pragma unroll
  for (int q = 0; q < 4; q++) B2[q] = b2[d + q];
  float Ac[4] = {1.f,1.f,1.f,1.f}, Bc[4] = {0.f,0.f,0.f,0.f};
  const int l0 = ch * 25;
  const u16x4 v4 = *(const u16x4*)(t4 + (size_t)(b * 40 + ch) * 300 + d);  // l/25 == ch
  for (int l = l0; l < l0 + 25; l++){
    u16x4 v0 = *(const u16x4*)(t0 + (size_t)(b * 1000 + l)        * 300 + d);
    u16x4 v1 = *(const u16x4*)(t1 + (size_t)(b * 500  + (l >> 1)) * 300 + d);
    u16x4 v2 = *(const u16x4*)(t2 + (size_t)(b * 250  + (l >> 2)) * 300 + d);
    u16x4 v3 = *(const u16x4*)(t3 + (size_t)(b * 100  + l / 10)   * 300 + d);
    u16x4 vz = *(const u16x4*)(z  + (size_t)(b * 1000 + l)        * 300 + d);
    #pragma unroll
    for (int q = 0; q < 4; q++){
      float B1q[3] = {B1[0][q], B1[1][q], B1[2][q]};
      float g  = gate_eval(bf2f(v0[q]), bf2f(v1[q]), bf2f(v2[q]), bf2f(v3[q]), bf2f(v4[q]),
                           W1, W2, B1q, B2[q]);
      Ac[q] = g * Ac[q];
      Bc[q] = g * Bc[q] + (1.f - g) * bf2f(vz[q]);
    }
  }
  *(float4*)(cA + (size_t)ch * 19200 + b * 300 + d) = make_float4(Ac[0], Ac[1], Ac[2], Ac[3]);
  *(float4*)(cB + (size_t)ch * 19200 + b * 300 + d) = make_float4(Bc[0], Bc[1], Bc[2], Bc[3]);
}

// ---------------- S2: combine 40 chunk composites -> chunk-initial c --------
__global__ void k_scan2(const float* __restrict__ cA, const float* __restrict__ cB,
                        float* __restrict__ cinit, int total){
  int i = blockIdx.x * blockDim.x + threadIdx.x;
  if (i >= total) return;
  float c = 0.f;
  for (int ch = 0; ch < 40; ch++){
    cinit[ch * 19200 + i] = c;
    c = cA[ch * 19200 + i] * c + cB[ch * 19200 + i];
  }
}

// ---------------- S3: final scan + output h = o*c ---------------------------
__global__ void k_scan3(const u16* __restrict__ t0, const u16* __restrict__ t1,
    const u16* __restrict__ t2, const u16* __restrict__ t3, const u16* __restrict__ t4,
    const u16* __restrict__ z, const u16* __restrict__ o,
    const float* __restrict__ cinit,
    const float* __restrict__ w1, const float* __restrict__ b1,
    const float* __restrict__ w2, const float* __restrict__ b2,
    float* __restrict__ out, int total)
{
  int i = blockIdx.x * blockDim.x + threadIdx.x;
  if (i >= total) return;
  int d4 = i % 75; int rest = i / 75; int ch = rest % 40; int b = rest / 40;
  const int d = d4 * 4;
  float W1[3][5], W2[3], B1[3][4], B2[4];
  #pragma unroll
  for (int t = 0; t < 3; t++){
    #pragma unroll
    for (int s = 0; s < 5; s++) W1[t][s] = w1[t * 5 + s];
    W2[t] = w2[t];
    #pragma unroll
    for (int q = 0; q < 4; q++) B1[t][q] = b1[t * 300 + d + q];
  }
  #pragma unroll
  for (int q = 0; q < 4; q++) B2[q] = b2[d + q];
  float c[4];
  {
    float4 ci = *(const float4*)(cinit + (size_t)ch * 19200 + b * 300 + d);
    c[0] = ci.x; c[1] = ci.y; c[2] = ci.z; c[3] = ci.w;
  }
  const int l0 = ch * 25;
  const u16x4 v4 = *(const u16x4*)(t4 + (size_t)(b * 40 + ch) * 300 + d);
  for (int l = l0; l < l0 + 25; l++){
    u16x4 v0 = *(const u16x4*)(t0 + (size_t)(b * 1000 + l)        * 300 + d);
    u16x4 v1 = *(const u16x4*)(t1 + (size_t)(b * 500  + (l >> 1)) * 300 + d);
    u16x4 v2 = *(const u16x4*)(t2 + (size_t)(b * 250  + (l >> 2)) * 300 + d);
    u16x4 v3 = *(const u16x4*)(t3 + (size_t)(b * 100  + l / 10)   * 300 + d);
    u16x4 vz = *(const u16x4*)(z  + (size_t)(b * 1000 + l)        * 300 + d);
    u16x4 vo = *(const u16x4*)(o  + (size_t)(b * 1000 + l)        * 300 + d);
    float4 res;
    #pragma unroll
    for (int q = 0; q < 4; q++){
      float B1q[3] = {B1[0][q], B1[1][q], B1[2][q]};
      float g  = gate_eval(bf2f(v0[q]), bf2f(v1[q]), bf2f(v2[q]), bf2f(v3[q]), bf2f(v4[q]),
                           W1, W2, B1q, B2[q]);
      c[q] = g * c[q] + (1.f - g) * bf2f(vz[q]);
      ((float*)&res)[q] = bf2f(vo[q]) * c[q];
    }
    *(float4*)(out + (size_t)(b * 1000 + l) * 300 + d) = res;
  }
}

extern "C" void kernel_launch(void* const* d_in, const int* in_sizes, int n_in,
                              void* d_out, int out_size, void* d_ws, size_t ws_size,
                              hipStream_t stream){
  const int*   article = (const int*)  d_in[0];
  const float* emb     = (const float*)d_in[1];
  const float* w_ce    = (const float*)d_in[2];
  const float* b_ce    = (const float*)d_in[3];
  const float* w1      = (const float*)d_in[4];
  const float* b1      = (const float*)d_in[5];
  const float* w2      = (const float*)d_in[6];
  const float* b2      = (const float*)d_in[7];
  const float* wz      = (const float*)d_in[8];
  const float* bz      = (const float*)d_in[9];
  const float* wo      = (const float*)d_in[10];
  const float* bo      = (const float*)d_in[11];
  float* out = (float*)d_out;
  char*  ws  = (char*)d_ws;

  // workspace layout (bytes, all 256-aligned)
  u16* x    = (u16*)(ws + 0UL);          // 64000x320 bf16  = 40,960,000
  u16* s2   = (u16*)(ws + 40960000UL);   // 32000x320       = 20,480,000
  u16* s4   = (u16*)(ws + 61440000UL);   // 16000x320       = 10,240,000
  u16* s10  = (u16*)(ws + 71680000UL);   //  6400x320       =  4,096,000
  u16* s25  = (u16*)(ws + 75776000UL);   //  2560x320       =  1,638,400
  u16* wT   = (u16*)(ws + 77414400UL);   // 7x320x320       =  1,433,600
  u16* t0   = (u16*)(ws + 78848000UL);   // 64000x300       = 38,400,000
  u16* t1   = (u16*)(ws + 117248000UL);  // 32000x300       = 19,200,000
  u16* t2   = (u16*)(ws + 136448000UL);  // 16000x300       =  9,600,000
  u16* t3   = (u16*)(ws + 146048000UL);  //  6400x300       =  3,840,000
  u16* t4   = (u16*)(ws + 149888000UL);  //  2560x300       =  1,536,000
  u16* zb   = (u16*)(ws + 151424000UL);  // 64000x300       = 38,400,000
  u16* ob   = (u16*)(ws + 189824000UL);  // 64000x300       = 38,400,000
  // scan composites live in the s2 region (dead after k_gemm_all):
  float* cA = (float*)(ws + 40960000UL); // 40x19200 f32 = 3,072,000
  float* cB = (float*)(ws + 44032000UL);
  float* ci = (float*)(ws + 47104000UL);
  (void)ws_size; (void)in_sizes; (void)n_in; (void)out_size;

  k_wprep     <<<2800, 256, 0, stream>>>(w_ce, wz, wo, wT, 716800);
  k_gather_seg<<<1000, 256, 0, stream>>>(article, emb, x, s2, s4, s10, 256000);
  k_s25       <<< 800, 256, 0, stream>>>(x, s25, 204800);

  k_gemm_all<<<1957, 512, 0, stream>>>(x, s2, s4, s10, s25, wT,
                                       t0, t1, t2, t3, t4, zb, ob,
                                       b_ce, bz, bo);

  k_scan1<<<750, 256, 0, stream>>>(t0, t1, t2, t3, t4, zb, w1, b1, w2, b2, cA, cB, 192000);
  k_scan2<<< 75, 256, 0, stream>>>(cA, cB, ci, 19200);
  k_scan3<<<750, 256, 0, stream>>>(t0, t1, t2, t3, t4, zb, ob, ci, w1, b1, w2, b2, out, 192000);
}